// Round 11
// baseline (48.715 us; speedup 1.0000x reference)
//
#include <hip/hip_runtime.h>

// Problem constants (from the JAX reference)
constexpr int B = 4;
constexpr int L = 4096;
constexpr int D = 2048;
constexpr float EPS = 1e-5f;

constexpr int CL = 16;         // L-rows per block (back to 16: 4 blocks/CU)
constexpr int R  = 4;          // rows per barrier group
constexpr int NG = CL / R;     // 4 main groups
constexpr int NW = 8;          // waves per block (512 threads)
constexpr int NCHUNK = L / CL; // 256
constexpr int NWG = NCHUNK * B;// 1024 blocks (divisible by 8 XCDs)

typedef float floatx4 __attribute__((ext_vector_type(4)));

__device__ __forceinline__ void load4(const float* __restrict__ p, float r[4]) {
    floatx4 v = *reinterpret_cast<const floatx4*>(p);
    r[0] = v.x; r[1] = v.y; r[2] = v.z; r[3] = v.w;
}

// Barrier that only drains LDS ops (lgkmcnt), NOT outstanding global loads
// (vmcnt): prefetched loads stay in flight across it.
__device__ __forceinline__ void light_barrier() {
    asm volatile("s_waitcnt lgkmcnt(0)" ::: "memory");
    __builtin_amdgcn_s_barrier();
    asm volatile("" ::: "memory");
}

// ---------------------------------------------------------------------------
// Fully fused: RMSNorm -> causal depthwise conv (K=4) -> SiLU, single pass.
// Depth-2 software pipeline: loads for group g+2 issued while group g
// finishes. LDS partial slots use mod-3 parity (write for group g+3 is two
// barriers after the read for group g -> race-free with the light barrier).
// CL=16 -> 1024 blocks = 4 blocks/CU: independent blocks decorrelate the
// barrier lockstep and keep the memory pipe fed.
// ---------------------------------------------------------------------------
__global__ __launch_bounds__(512) void fused_kernel(const float* __restrict__ x,
                                                    const float* __restrict__ nw,
                                                    const float* __restrict__ cw,
                                                    float* __restrict__ out) {
    const int t = threadIdx.x;          // 0..511
    const int wave = t >> 6;
    const int lane = t & 63;

    // XCD-aware swizzle: consecutive work ids (adjacent L-chunks, sharing
    // halo rows) land on the same XCD's L2. NWG % 8 == 0 -> bijective.
    const int bid = blockIdx.x;
    const int swz = (bid & 7) * (NWG / 8) + (bid >> 3);
    const int b = swz / NCHUNK;
    const int chunk = swz % NCHUNK;
    const int l0 = chunk * CL;
    const int d = t * 4;

    const float* xb = x + (size_t)b * L * D + d;
    float* ob = out + (size_t)b * L * D + d;

    __shared__ float s_red[3][R][NW];   // mod-3 parity for main groups
    __shared__ float s_halo[3][NW];

    float nwv[4], wv[4][4];
    load4(nw + d, nwv);
    #pragma unroll
    for (int k = 0; k < 4; ++k) load4(cw + k * D + d, wv[k]);  // (K,1,D)

    // ---- Prologue: issue halo(3) + grp0(4) + grp1(4) loads: 11 in flight
    float hx[3][4];
    #pragma unroll
    for (int j = 0; j < 3; ++j) {
        const int l = l0 - 3 + j;
        hx[j][0] = hx[j][1] = hx[j][2] = hx[j][3] = 0.0f;
        if (l >= 0) load4(xb + (size_t)l * D, hx[j]);
    }
    float cur[R][4], nxt[R][4], nxt2[R][4];
    #pragma unroll
    for (int r = 0; r < R; ++r)
        load4(xb + (size_t)(l0 + r) * D, cur[r]);
    #pragma unroll
    for (int r = 0; r < R; ++r)
        load4(xb + (size_t)(l0 + R + r) * D, nxt[r]);

    // Reduce halo + grp0 together, one barrier
    #pragma unroll
    for (int j = 0; j < 3; ++j) {
        float s = hx[j][0]*hx[j][0] + hx[j][1]*hx[j][1]
                + hx[j][2]*hx[j][2] + hx[j][3]*hx[j][3];
        #pragma unroll
        for (int off = 32; off > 0; off >>= 1)
            s += __shfl_down(s, off, 64);
        if (lane == 0) s_halo[j][wave] = s;
    }
    #pragma unroll
    for (int r = 0; r < R; ++r) {
        float s = cur[r][0]*cur[r][0] + cur[r][1]*cur[r][1]
                + cur[r][2]*cur[r][2] + cur[r][3]*cur[r][3];
        #pragma unroll
        for (int off = 32; off > 0; off >>= 1)
            s += __shfl_down(s, off, 64);
        if (lane == 0) s_red[0][r][wave] = s;
    }
    light_barrier();

    // Finish halo -> window (VALU only)
    float win[3][4];
    #pragma unroll
    for (int j = 0; j < 3; ++j) {
        float tot = 0.0f;
        #pragma unroll
        for (int w = 0; w < NW; ++w) tot += s_halo[j][w];
        float irms = rsqrtf(tot * (1.0f / D) + EPS);
        #pragma unroll
        for (int i = 0; i < 4; ++i) win[j][i] = hx[j][i] * irms * nwv[i];
    }

    // ---- Main loop: finish(g) reads slot g%3 (written in iter g-1);
    //      reduce(g+1) writes slot (g+1)%3; loads for g+2 issued now.
    #pragma unroll
    for (int g = 0; g < NG; ++g) {
        // reduce next group's rows (loaded one full iteration ago)
        if (g + 1 < NG) {
            #pragma unroll
            for (int r = 0; r < R; ++r) {
                float s = nxt[r][0]*nxt[r][0] + nxt[r][1]*nxt[r][1]
                        + nxt[r][2]*nxt[r][2] + nxt[r][3]*nxt[r][3];
                #pragma unroll
                for (int off = 32; off > 0; off >>= 1)
                    s += __shfl_down(s, off, 64);
                if (lane == 0) s_red[(g + 1) % 3][r][wave] = s;
            }
        }

        // issue loads for group g+2 (have reduce+barrier+finish to land)
        if (g + 2 < NG) {
            #pragma unroll
            for (int r = 0; r < R; ++r)
                load4(xb + (size_t)(l0 + (g + 2) * R + r) * D, nxt2[r]);
        }

        light_barrier();

        // finish group g: partials from slot g%3, conv + SiLU + nt-store
        #pragma unroll
        for (int r = 0; r < R; ++r) {
            float tot = 0.0f;
            #pragma unroll
            for (int w = 0; w < NW; ++w) tot += s_red[g % 3][r][w];
            const float irms = rsqrtf(tot * (1.0f / D) + EPS);

            float c[4], y[4];
            #pragma unroll
            for (int i = 0; i < 4; ++i) {
                c[i] = cur[r][i] * irms * nwv[i];
                y[i] = wv[0][i]*win[0][i] + wv[1][i]*win[1][i]
                     + wv[2][i]*win[2][i] + wv[3][i]*c[i];
                y[i] = y[i] / (1.0f + __expf(-y[i]));   // SiLU
            }
            floatx4 o;
            o.x = y[0]; o.y = y[1]; o.z = y[2]; o.w = y[3];
            __builtin_nontemporal_store(o,
                reinterpret_cast<floatx4*>(ob + (size_t)(l0 + g * R + r) * D));

            #pragma unroll
            for (int i = 0; i < 4; ++i) {
                win[0][i] = win[1][i];
                win[1][i] = win[2][i];
                win[2][i] = c[i];
            }
        }

        // rotate row buffers (loop fully unrolled -> pure register renaming)
        #pragma unroll
        for (int r = 0; r < R; ++r)
            #pragma unroll
            for (int i = 0; i < 4; ++i) {
                cur[r][i] = nxt[r][i];
                nxt[r][i] = nxt2[r][i];
            }
    }
}

extern "C" void kernel_launch(void* const* d_in, const int* in_sizes, int n_in,
                              void* d_out, int out_size, void* d_ws, size_t ws_size,
                              hipStream_t stream) {
    const float* x  = (const float*)d_in[0];   // (B, L, D) fp32
    const float* nw = (const float*)d_in[1];   // (D,) fp32
    const float* cw = (const float*)d_in[2];   // (K, 1, D) fp32
    float* out = (float*)d_out;                // (B, L, D) fp32

    fused_kernel<<<NWG, 512, 0, stream>>>(x, nw, cw, out);
}

// Round 12
// 47.638 us; speedup vs baseline: 1.0226x; 1.0226x over previous
//
#include <hip/hip_runtime.h>

// Problem constants (from the JAX reference)
constexpr int B = 4;
constexpr int L = 4096;
constexpr int D = 2048;
constexpr float EPS = 1e-5f;

constexpr int CL = 32;         // L-rows per block
constexpr int R  = 4;          // rows per barrier group
constexpr int NG = CL / R;     // 8 main groups
constexpr int NW = 8;          // waves per block (512 threads)
constexpr int NCHUNK = L / CL; // 128
constexpr int NWG = NCHUNK * B;// 512 blocks (divisible by 8 XCDs)

typedef float floatx4 __attribute__((ext_vector_type(4)));

__device__ __forceinline__ void load4(const float* __restrict__ p, float r[4]) {
    floatx4 v = *reinterpret_cast<const floatx4*>(p);
    r[0] = v.x; r[1] = v.y; r[2] = v.z; r[3] = v.w;
}

// Barrier that only drains LDS ops (lgkmcnt), NOT outstanding global loads
// (vmcnt): prefetched loads stay in flight across it.
__device__ __forceinline__ void light_barrier() {
    asm volatile("s_waitcnt lgkmcnt(0)" ::: "memory");
    __builtin_amdgcn_s_barrier();
    asm volatile("" ::: "memory");
}

// ---------------------------------------------------------------------------
// Fully fused: RMSNorm -> causal depthwise conv (K=4) -> SiLU, single pass.
// Depth-2 software pipeline (loads for group g+2 issued while group g
// finishes); mod-3 LDS parity. __launch_bounds__(512, 2): the grid gives
// only 2 blocks/CU, so allow the allocator up to ~256 VGPRs — keeps the
// depth-2 prefetch genuinely register-resident instead of sunk.
// ---------------------------------------------------------------------------
__global__ __launch_bounds__(512, 2) void fused_kernel(const float* __restrict__ x,
                                                       const float* __restrict__ nw,
                                                       const float* __restrict__ cw,
                                                       float* __restrict__ out) {
    const int t = threadIdx.x;          // 0..511
    const int wave = t >> 6;
    const int lane = t & 63;

    // XCD-aware swizzle: consecutive work ids (adjacent L-chunks, sharing
    // halo rows) land on the same XCD's L2. NWG % 8 == 0 -> bijective.
    const int bid = blockIdx.x;
    const int swz = (bid & 7) * (NWG / 8) + (bid >> 3);
    const int b = swz / NCHUNK;
    const int chunk = swz % NCHUNK;
    const int l0 = chunk * CL;
    const int d = t * 4;

    const float* xb = x + (size_t)b * L * D + d;
    float* ob = out + (size_t)b * L * D + d;

    __shared__ float s_red[3][R][NW];   // mod-3 parity for main groups
    __shared__ float s_halo[3][NW];

    float nwv[4], wv[4][4];
    load4(nw + d, nwv);
    #pragma unroll
    for (int k = 0; k < 4; ++k) load4(cw + k * D + d, wv[k]);  // (K,1,D)

    // ---- Prologue: issue halo(3) + grp0(4) + grp1(4) loads: 11 in flight
    float hx[3][4];
    #pragma unroll
    for (int j = 0; j < 3; ++j) {
        const int l = l0 - 3 + j;
        hx[j][0] = hx[j][1] = hx[j][2] = hx[j][3] = 0.0f;
        if (l >= 0) load4(xb + (size_t)l * D, hx[j]);
    }
    float cur[R][4], nxt[R][4], nxt2[R][4];
    #pragma unroll
    for (int r = 0; r < R; ++r)
        load4(xb + (size_t)(l0 + r) * D, cur[r]);
    #pragma unroll
    for (int r = 0; r < R; ++r)
        load4(xb + (size_t)(l0 + R + r) * D, nxt[r]);

    // Reduce halo + grp0 together, one barrier
    #pragma unroll
    for (int j = 0; j < 3; ++j) {
        float s = hx[j][0]*hx[j][0] + hx[j][1]*hx[j][1]
                + hx[j][2]*hx[j][2] + hx[j][3]*hx[j][3];
        #pragma unroll
        for (int off = 32; off > 0; off >>= 1)
            s += __shfl_down(s, off, 64);
        if (lane == 0) s_halo[j][wave] = s;
    }
    #pragma unroll
    for (int r = 0; r < R; ++r) {
        float s = cur[r][0]*cur[r][0] + cur[r][1]*cur[r][1]
                + cur[r][2]*cur[r][2] + cur[r][3]*cur[r][3];
        #pragma unroll
        for (int off = 32; off > 0; off >>= 1)
            s += __shfl_down(s, off, 64);
        if (lane == 0) s_red[0][r][wave] = s;
    }
    light_barrier();

    // Finish halo -> window (VALU only)
    float win[3][4];
    #pragma unroll
    for (int j = 0; j < 3; ++j) {
        float tot = 0.0f;
        #pragma unroll
        for (int w = 0; w < NW; ++w) tot += s_halo[j][w];
        float irms = rsqrtf(tot * (1.0f / D) + EPS);
        #pragma unroll
        for (int i = 0; i < 4; ++i) win[j][i] = hx[j][i] * irms * nwv[i];
    }

    // ---- Main loop: finish(g) reads slot g%3 (written in iter g-1);
    //      reduce(g+1) writes slot (g+1)%3; loads for g+2 issued now.
    #pragma unroll
    for (int g = 0; g < NG; ++g) {
        // reduce next group's rows (loaded one full iteration ago)
        if (g + 1 < NG) {
            #pragma unroll
            for (int r = 0; r < R; ++r) {
                float s = nxt[r][0]*nxt[r][0] + nxt[r][1]*nxt[r][1]
                        + nxt[r][2]*nxt[r][2] + nxt[r][3]*nxt[r][3];
                #pragma unroll
                for (int off = 32; off > 0; off >>= 1)
                    s += __shfl_down(s, off, 64);
                if (lane == 0) s_red[(g + 1) % 3][r][wave] = s;
            }
        }

        // issue loads for group g+2 (have reduce+barrier+finish to land)
        if (g + 2 < NG) {
            #pragma unroll
            for (int r = 0; r < R; ++r)
                load4(xb + (size_t)(l0 + (g + 2) * R + r) * D, nxt2[r]);
        }

        light_barrier();

        // finish group g: partials from slot g%3, conv + SiLU + nt-store
        #pragma unroll
        for (int r = 0; r < R; ++r) {
            float tot = 0.0f;
            #pragma unroll
            for (int w = 0; w < NW; ++w) tot += s_red[g % 3][r][w];
            const float irms = rsqrtf(tot * (1.0f / D) + EPS);

            float c[4], y[4];
            #pragma unroll
            for (int i = 0; i < 4; ++i) {
                c[i] = cur[r][i] * irms * nwv[i];
                y[i] = wv[0][i]*win[0][i] + wv[1][i]*win[1][i]
                     + wv[2][i]*win[2][i] + wv[3][i]*c[i];
                y[i] = y[i] / (1.0f + __expf(-y[i]));   // SiLU
            }
            floatx4 o;
            o.x = y[0]; o.y = y[1]; o.z = y[2]; o.w = y[3];
            __builtin_nontemporal_store(o,
                reinterpret_cast<floatx4*>(ob + (size_t)(l0 + g * R + r) * D));

            #pragma unroll
            for (int i = 0; i < 4; ++i) {
                win[0][i] = win[1][i];
                win[1][i] = win[2][i];
                win[2][i] = c[i];
            }
        }

        // rotate row buffers (loop fully unrolled -> pure register renaming)
        #pragma unroll
        for (int r = 0; r < R; ++r)
            #pragma unroll
            for (int i = 0; i < 4; ++i) {
                cur[r][i] = nxt[r][i];
                nxt[r][i] = nxt2[r][i];
            }
    }
}

extern "C" void kernel_launch(void* const* d_in, const int* in_sizes, int n_in,
                              void* d_out, int out_size, void* d_ws, size_t ws_size,
                              hipStream_t stream) {
    const float* x  = (const float*)d_in[0];   // (B, L, D) fp32
    const float* nw = (const float*)d_in[1];   // (D,) fp32
    const float* cw = (const float*)d_in[2];   // (K, 1, D) fp32
    float* out = (float*)d_out;                // (B, L, D) fp32

    fused_kernel<<<NWG, 512, 0, stream>>>(x, nw, cw, out);
}